// Round 2
// baseline (340.793 us; speedup 1.0000x reference)
//
#include <hip/hip_runtime.h>

// MRPCEN: multi-rate PCEN.
//   x: (B=16, F=128, T=4096) f32; alpha_log/delta_log/r_log: (F,) f32
//   out: (B, 4, F, T) f32
// m[b,f,0]=x[b,f,0]; m[t]=(1-s)m[t-1]+s x[t]  (4 s-values, compile-time consts)
// out = (x*(EPS+m)^(-alpha) + delta)^r - delta^r
//
// v3: ONE WAVE per (row, s-value). Block = 256 threads = 4 waves, wave w owns
// s-value w for the whole 4096-row; lane owns 64 CONTIGUOUS elements.
// The 64-lane shuffle scan IS the full-row scan: no LDS, no barrier, no
// cross-wave combine, 6 shuffles per wave (v1 had 28 + barrier + carry loop).
// Grid 2048 x 256 = 8192 waves = exactly one fully-resident round
// (8 waves/SIMD at VGPR<=64). x row is read twice (recurrence + replay) but
// stays in L1/L2 (block working set = 16 KB shared by its 4 waves).
// Stores: lane-strided float4, but each 64B line is one lane's 4 consecutive
// k-chunks -> completes within ~100 cyc -> merges in writeback L2.
// Initial condition folded by seeding carry with omn^(64*lane)*x0
// ((1-s)x0+s*x0=x0).
//
// NOTE: no <math.h> include — glibc's __MATHCALL declares __exp2f etc. and
// collides with HIP device intrinsics. Use __builtin_amdgcn_* directly.

#define EPS_C 1e-5f

__device__ __forceinline__ float fexp2(float v) { return __builtin_amdgcn_exp2f(v); }
__device__ __forceinline__ float flog2(float v) { return __builtin_amdgcn_logf(v); }
__device__ __forceinline__ float fpow(float a, float b) { return fexp2(b * flog2(a)); }
__device__ __forceinline__ float fexp(float v) { return fexp2(v * 1.44269504f); }

__global__ __launch_bounds__(256, 8)
void pcen_kernel(const float* __restrict__ x,
                 const float* __restrict__ alpha_log,
                 const float* __restrict__ delta_log,
                 const float* __restrict__ r_log,
                 float* __restrict__ out)
{
    const int row  = blockIdx.x;          // b*128 + f
    const int f    = row & 127;
    const int b    = row >> 7;
    const int tid  = threadIdx.x;         // 0..255
    const int lane = tid & 63;
    const int w    = tid >> 6;            // wave id == s-value index, 0..3

    // Per-wave s-value (wave-uniform; NO runtime-indexed array -> no scratch)
    const float Tv = (w == 0) ? 0.015f : (w == 1) ? 0.06f : (w == 2) ? 0.25f : 1.0f;
    const float t   = Tv * 86.1328125f;   // 44100/512
    const float t2  = t * t;
    const float s   = (__builtin_sqrtf(1.0f + 4.0f * t2) - 1.0f) / (2.0f * t2);
    const float omn = 1.0f - s;

    const float4* __restrict__ xrow4 = (const float4*)(x + (size_t)row * 4096);

    // ---- pass A: zero-init local recurrence over lane's 64 contiguous elems
    float p = 0.0f;
    float xfirst = 0.0f;
#pragma unroll
    for (int k = 0; k < 16; ++k) {
        float4 v = xrow4[lane * 16 + k];
        if (k == 0) xfirst = v.x;
        p = fmaf(omn, p, s * v.x);
        p = fmaf(omn, p, s * v.y);
        p = fmaf(omn, p, s * v.z);
        p = fmaf(omn, p, s * v.w);
    }
    const float x0 = __shfl(xfirst, 0);   // row's first element (wave-local bcast)

    // ---- wave inclusive scan of segment tails, segment decay omn^64
    float c = omn * omn;                  // omn^2
    c = c * c; c = c * c; c = c * c; c = c * c; c = c * c;   // omn^64
    float q = p;
#pragma unroll
    for (int k = 0; k < 6; ++k) {
        int d = 1 << k;
        float tsh = __shfl_up(q, d);
        if (lane >= d) q = fmaf(c, tsh, q);
        c = c * c;
    }
    float qx = __shfl_up(q, 1);           // exclusive scan
    if (lane == 0) qx = 0.0f;

    // carry entering this lane's segment: M(64*lane-1) = omn^(64*lane)*x0 + qx
    const float l2omn = flog2(omn);
    const float dlane = fexp2((float)(64 * lane) * l2omn);
    float m = fmaf(dlane, x0, qx);

    // Per-F parameters (block-uniform -> scalarized)
    const float al = alpha_log[f], dlg = delta_log[f], rl = r_log[f];
    const float nalpha  = -fexp(al);
    const float delta   =  fexp(dlg);
    const float r       =  fexp(rl);
    const float delta_r =  fexp(r * dlg); // delta^r = exp(r*log(delta))

    float4* __restrict__ out4 =
        (float4*)(out + (((size_t)(b * 4 + w)) * 128 + f) * 4096);

    // ---- pass B: replay from true carry + pcen + store (x re-read hits L1/L2)
#pragma unroll
    for (int k = 0; k < 16; ++k) {
        float4 v = xrow4[lane * 16 + k];
        float4 o;
        m = fmaf(omn, m, s * v.x);
        o.x = fpow(fmaf(v.x, fpow(EPS_C + m, nalpha), delta), r) - delta_r;
        m = fmaf(omn, m, s * v.y);
        o.y = fpow(fmaf(v.y, fpow(EPS_C + m, nalpha), delta), r) - delta_r;
        m = fmaf(omn, m, s * v.z);
        o.z = fpow(fmaf(v.z, fpow(EPS_C + m, nalpha), delta), r) - delta_r;
        m = fmaf(omn, m, s * v.w);
        o.w = fpow(fmaf(v.w, fpow(EPS_C + m, nalpha), delta), r) - delta_r;
        out4[lane * 16 + k] = o;
    }
}

extern "C" void kernel_launch(void* const* d_in, const int* in_sizes, int n_in,
                              void* d_out, int out_size, void* d_ws, size_t ws_size,
                              hipStream_t stream) {
    const float* x  = (const float*)d_in[0];
    const float* al = (const float*)d_in[1];
    const float* dl = (const float*)d_in[2];
    const float* rl = (const float*)d_in[3];
    float* out = (float*)d_out;
    const int rows = in_sizes[0] / 4096;   // B*F = 2048
    pcen_kernel<<<rows, 256, 0, stream>>>(x, al, dl, rl, out);
}

// Round 4
// 169.338 us; speedup vs baseline: 2.0125x; 2.0125x over previous
//
#include <hip/hip_runtime.h>

// MRPCEN: multi-rate PCEN.
//   x: (B=16, F=128, T=4096) f32; alpha_log/delta_log/r_log: (F,) f32
//   out: (B, 4, F, T) f32
// m[b,f,0]=x[b,f,0]; m[t]=(1-s)m[t-1]+s x[t]  (4 s-values, compile-time consts)
// out = (x*(EPS+m)^(-alpha) + delta)^r - delta^r
//
// v5 = v4 with the nontemporal builtins fed native clang ext_vector types
// (HIP_vector_type float4 is a struct -> builtin rejects it; f32x4 is the
// same 16B layout and emits the same global_{load,store}_dwordx4, with nt).
//
// Rationale (from v3's counters): v1-structure is memory-roofline-optimal —
// every load/store instruction covers a contiguous 16KB span. v3's scattered
// stores showed WRITE 3.4x + FETCH 3.4x (L2 write-allocate of out lines);
// nt hints avoid allocate/pollution for write-once out and read-once x.
// Back-solve: v1 kernel ~= 25us (= 168MB ideal / 6.8TB/s); bench carries
// ~140us of fixed harness fill overhead.
//
// NOTE: no <math.h> include — glibc's __MATHCALL declares __exp2f etc. and
// collides with HIP device intrinsics. Use __builtin_amdgcn_* directly.

#define EPS_C 1e-5f

typedef float f32x4 __attribute__((ext_vector_type(4)));

__device__ __forceinline__ float fexp2(float v) { return __builtin_amdgcn_exp2f(v); }
__device__ __forceinline__ float flog2(float v) { return __builtin_amdgcn_logf(v); }
__device__ __forceinline__ float fpow(float a, float b) { return fexp2(b * flog2(a)); }
__device__ __forceinline__ float fexp(float v) { return fexp2(v * 1.44269504f); }

__global__ __launch_bounds__(1024)
void pcen_kernel(const float* __restrict__ x,
                 const float* __restrict__ alpha_log,
                 const float* __restrict__ delta_log,
                 const float* __restrict__ r_log,
                 float* __restrict__ out)
{
    const int row  = blockIdx.x;          // b*128 + f
    const int f    = row & 127;
    const int b    = row >> 7;
    const int tid  = threadIdx.x;         // 0..1023
    const int lane = tid & 63;
    const int w    = tid >> 6;            // wave id 0..15

    __shared__ float wq[4][16];           // per-s, per-wave inclusive scan tails
    __shared__ float sh_x0;

    const f32x4* __restrict__ xrow4 = (const f32x4*)(x + (size_t)row * 4096);
    f32x4 xv = __builtin_nontemporal_load(xrow4 + tid);
    if (tid == 0) sh_x0 = xv.x;

    // s-values from module constants (const-folded by the compiler)
    const float Tv[4] = {0.015f, 0.06f, 0.25f, 1.0f};
    float s_arr[4], omn_arr[4];
#pragma unroll
    for (int i = 0; i < 4; ++i) {
        float t  = Tv[i] * 86.1328125f;   // 44100/512
        float t2 = t * t;
        float s  = (__builtin_sqrtf(1.0f + 4.0f * t2) - 1.0f) / (2.0f * t2);
        s_arr[i]   = s;
        omn_arr[i] = 1.0f - s;
    }

    // Phase 1: per-s local recurrence + wave scan (no barrier yet)
    float qxv[4];
#pragma unroll
    for (int i = 0; i < 4; ++i) {
        const float s = s_arr[i], omn = omn_arr[i];
        // local 4-element recurrence, zero initial state
        float p = s * xv.x;
        p = fmaf(omn, p, s * xv.y);
        p = fmaf(omn, p, s * xv.z);
        p = fmaf(omn, p, s * xv.w);
        // wave-level inclusive scan of segment outputs, segment decay D4=omn^4
        float q = p;
        float c = omn * omn; c = c * c;   // omn^4
#pragma unroll
        for (int k = 0; k < 6; ++k) {
            int d = 1 << k;
            float tsh = __shfl_up(q, d);
            if (lane >= d) q = fmaf(c, tsh, q);
            c = c * c;
        }
        float qx = __shfl_up(q, 1);       // within-wave exclusive
        if (lane == 0) qx = 0.0f;
        qxv[i] = qx;
        if (lane == 63) wq[i][w] = q;
    }
    __syncthreads();                       // the only barrier

    // Per-F parameters (block-uniform -> scalarized)
    const float al = alpha_log[f], dl = delta_log[f], rl = r_log[f];
    const float nalpha  = -fexp(al);
    const float delta   =  fexp(dl);
    const float r       =  fexp(rl);
    const float delta_r =  fexp(r * dl);  // delta^r = exp(r*log(delta))

    const float x0 = sh_x0;
    f32x4* __restrict__ out4 = (f32x4*)out;

#pragma unroll
    for (int i = 0; i < 4; ++i) {
        const float s = s_arr[i], omn = omn_arr[i];
        const float l2omn = flog2(omn);
        const float Dw = fexp2(256.0f * l2omn);      // omn^256 (wave decay)
        // carry entering this wave; seed with M(-1)=x0 so m[0]=x[0] exactly
        float Q = x0;
        for (int v = 0; v < w; ++v) Q = fmaf(Dw, Q, wq[i][v]);
        // carry entering this thread's segment
        const float dl4 = fexp2((float)(4 * lane) * l2omn); // omn^(4*lane)
        const float E = fmaf(dl4, Q, qxv[i]);
        // replay recurrence from true carry
        float m0 = fmaf(omn, E,  s * xv.x);
        float m1 = fmaf(omn, m0, s * xv.y);
        float m2 = fmaf(omn, m1, s * xv.z);
        float m3 = fmaf(omn, m2, s * xv.w);
        // pcen = (x*(EPS+m)^(-alpha) + delta)^r - delta^r
        f32x4 o;
        o.x = fpow(fmaf(xv.x, fpow(EPS_C + m0, nalpha), delta), r) - delta_r;
        o.y = fpow(fmaf(xv.y, fpow(EPS_C + m1, nalpha), delta), r) - delta_r;
        o.z = fpow(fmaf(xv.z, fpow(EPS_C + m2, nalpha), delta), r) - delta_r;
        o.w = fpow(fmaf(xv.w, fpow(EPS_C + m3, nalpha), delta), r) - delta_r;

        const size_t obase4 = ((size_t)((b * 4 + i) * 128 + f)) * 1024; // /4
        __builtin_nontemporal_store(o, out4 + obase4 + tid);
    }
}

extern "C" void kernel_launch(void* const* d_in, const int* in_sizes, int n_in,
                              void* d_out, int out_size, void* d_ws, size_t ws_size,
                              hipStream_t stream) {
    const float* x  = (const float*)d_in[0];
    const float* al = (const float*)d_in[1];
    const float* dl = (const float*)d_in[2];
    const float* rl = (const float*)d_in[3];
    float* out = (float*)d_out;
    const int rows = in_sizes[0] / 4096;   // B*F = 2048
    pcen_kernel<<<rows, 1024, 0, stream>>>(x, al, dl, rl, out);
}